// Round 4
// baseline (1348.285 us; speedup 1.0000x reference)
//
#include <hip/hip_runtime.h>
#include <stdint.h>
#include <string.h>

// Problem dims (fixed by the reference)
#define BDIM   4096
#define INDIM  1024
#define XDIM   2048
#define OUTDIM 512
#define MCH    (BDIM / 16)   // 256 row-chunks along M for packed activations

#define LO_SCALE 2048.0f         // 2^11: lifts fp16 lo-plane out of subnormals
#define INV_LO_SCALE (1.0f / 2048.0f)

typedef _Float16 f16x8 __attribute__((ext_vector_type(8)));
typedef float f32x4 __attribute__((ext_vector_type(4)));
typedef unsigned short u16x8 __attribute__((ext_vector_type(8)));
typedef unsigned short u16x4 __attribute__((ext_vector_type(4)));

__device__ __forceinline__ unsigned short h2u(_Float16 h) {
  unsigned short u;
  memcpy(&u, &h, 2);
  return u;
}

// split f32 into hi fp16 + scaled-lo fp16 (combined ~22 mantissa bits)
__device__ __forceinline__ void split_h(float v, unsigned short& h,
                                        unsigned short& l) {
  _Float16 hh = (_Float16)v;                       // RTNE
  float r = v - (float)hh;                         // exact
  _Float16 ll = (_Float16)(r * LO_SCALE);          // |r|*2^11 <= |v|, no inf
  h = h2u(hh);
  l = h2u(ll);
}

// async global->LDS, 16B per lane; LDS dest wave-uniform base + lane*16
__device__ __forceinline__ void gld_lds16(const void* g, void* l) {
  __builtin_amdgcn_global_load_lds(
      (const __attribute__((address_space(1))) uint32_t*)g,
      (__attribute__((address_space(3))) uint32_t*)l, 16, 0, 0);
}

// fused RandomActivation + clip (relu/sigmoid/tanh/leaky(.1)/selu), libm-grade
__device__ __forceinline__ float rand_act(float v, int a, float mo) {
  float r;
  if (a == 0) {
    r = fmaxf(v, 0.0f);
  } else if (a == 1) {
    r = 1.0f / (1.0f + expf(-v));
  } else if (a == 2) {
    r = tanhf(v);
  } else if (a == 3) {
    r = (v >= 0.0f) ? v : 0.1f * v;
  } else {  // selu (matches jax: scale * where(v>0, v, alpha*expm1(v)))
    r = (v > 0.0f) ? 1.0507009873554805f * v
                   : 1.7580993408473766f * expm1f(v);
  }
  return fminf(r, mo);
}

// ---------------------------------------------------------------------------
// PACKED LAYOUT: tensor X[rows][K] is stored as
//   packed[k/32][row/16][lane(64)][8 halfs],
// lane = quad*16 + m16 holding X[chunkrow*16 + m16][kstep*32 + quad*8 + j].
// Each (kstep,chunk) = contiguous 1 KB: staging DMA is consecutive-lane-
// contiguous AND compute ds_read_b128 is contiguous (zero conflicts).
// Concat along K = packed tensors back-to-back.
// ---------------------------------------------------------------------------

// x[BDIM][Kin] f32 row-major -> packed hi/lo planes. grid(Kin/32, BDIM/64)x256
__global__ void pack_x(const float* __restrict__ s,
                       unsigned short* __restrict__ dh,
                       unsigned short* __restrict__ dl, int Kin) {
  int ks = blockIdx.x;
  int mblk = blockIdx.y;
  int cc = threadIdx.x >> 6;        // chunk within 64-row group
  int lane = threadIdx.x & 63;
  int m16 = lane & 15, quad = lane >> 4;
  int row = mblk * 64 + cc * 16 + m16;
  const float* src = s + (size_t)row * Kin + ks * 32 + quad * 8;
  size_t o = ((size_t)ks * MCH + mblk * 4 + cc) * 512 + lane * 8;
  float4 v0 = *(const float4*)src;
  float4 v1 = *(const float4*)(src + 4);
  float vs[8] = {v0.x, v0.y, v0.z, v0.w, v1.x, v1.y, v1.z, v1.w};
  u16x8 vh, vl;
#pragma unroll
  for (int j = 0; j < 8; j++) {
    unsigned short h, l;
    split_h(vs[j], h, l);
    vh[j] = h;
    vl[j] = l;
  }
  *(u16x8*)(dh + o) = vh;
  *(u16x8*)(dl + o) = vl;
}

// W[K][N] f32 row-major -> packed-BT hi/lo (rows=N, Kdim=K).
// grid(N/32, K/32), block(32,8).
__global__ void pack_w(const float* __restrict__ W,
                       unsigned short* __restrict__ dh,
                       unsigned short* __restrict__ dl, int K, int N) {
  __shared__ float t[32][33];       // t[k'][n']
  int n0 = blockIdx.x * 32, k0 = blockIdx.y * 32;
  int tx = threadIdx.x, ty = threadIdx.y;
#pragma unroll
  for (int i = 0; i < 32; i += 8)
    t[ty + i][tx] = W[(size_t)(k0 + ty + i) * N + n0 + tx];
  __syncthreads();
  int tt = ty * 32 + tx;            // 0..255
  int ci = tt >> 7;                 // n-chunk 0/1
  int rem = tt & 127;
  int lane = rem >> 1;
  int j4 = (rem & 1) * 4;
  int m16 = lane & 15, quad = lane >> 4;
  size_t o = ((size_t)(k0 >> 5) * (N >> 4) + (n0 >> 4) + ci) * 512 +
             lane * 8 + j4;
  u16x4 vh, vl;
#pragma unroll
  for (int jj = 0; jj < 4; jj++) {
    float v = t[quad * 8 + j4 + jj][ci * 16 + m16];
    unsigned short h, l;
    split_h(v, h, l);
    vh[jj] = h;
    vl[jj] = l;
  }
  *(u16x4*)(dh + o) = vh;
  *(u16x4*)(dl + o) = vl;
}

// C[M,N] = act( A[M,K] @ BT[N,K]^T + bias ), split-fp16 (3-term) precision.
// acc1 = hi*hi; acc2 = hi*lo' + lo'*hi at scale 2^11. Final = acc1+acc2/2^11.
//
// Round-13 structure (R3 post-mortem: sync structure was NOT the constraint;
// per-FLOP overhead texture is — R0==R3 within 2% at MfmaUtil ~46%):
//  - WAVE-TILE 64x64 (block 128x128, 4 waves in 2x2): 48 MFMA per K-step per
//    wave against the SAME 8 ds_reads -> per-CU LDS A-read traffic HALVES
//    (was x4-redundant across 1x4 waves), loop/barrier overhead per FLOP
//    halves, MFMA cluster ILP doubles (932-cyc bursts).
//  - acc 128 AGPR + B-dbuf 64 VGPR -> ~230 unified regs -> 2 waves/SIMD
//    (8 waves/CU, 2 blocks/CU): the m201-proven "ILP instead of TLP" class.
//  - Schedule = R3's counted-vmcnt single-barrier window (proven correct),
//    ledger doubled: stage=8, loadB=8; manual waits vmcnt(8).
//  - linear block order (proven: FETCH ~330 MB, B re-reads L3-warm).
// Grid (N/128, M/128), 256 threads.
template <bool OUT_F16>
__global__ __launch_bounds__(256, 2) void gemm_split_act(
    const short* __restrict__ A1h, const short* __restrict__ A1l,
    const short* __restrict__ A2h, const short* __restrict__ A2l,
    const short* __restrict__ BTh, const short* __restrict__ BTl,
    const float* __restrict__ bias, const float* __restrict__ mo,
    const int* __restrict__ aid, unsigned short* __restrict__ Ch,
    unsigned short* __restrict__ Cl, float* __restrict__ Cf, int N, int K,
    int Ksplit) {
  __shared__ short lds0[2 * 16 * 512];   // 32 KB: [sub][16 chunks][512]
  __shared__ short lds1[2 * 16 * 512];   // chunks 0-7 hi, 8-15 lo (128 rows)

  const int tid = threadIdx.x;
  const int lane = tid & 63;
  const int wave = tid >> 6;
  const int wm = wave >> 1;         // 0..1: M-half of block tile
  const int wn = wave & 1;          // 0..1: N-half of block tile
  const int m16 = lane & 15, quad = lane >> 4;

  const int blockN = blockIdx.x * 128;   // linear order (proven locality)
  const int blockM = blockIdx.y * 128;

  f32x4 acc1[4][4];  // hi*hi
  f32x4 acc2[4][4];  // (hi*lo' + lo'*hi), scale 2^11
#pragma unroll
  for (int i = 0; i < 4; i++)
#pragma unroll
    for (int j = 0; j < 4; j++) {
      acc1[i][j] = (f32x4){0.f, 0.f, 0.f, 0.f};
      acc2[i][j] = (f32x4){0.f, 0.f, 0.f, 0.f};
    }

  const int KSTEPS = K >> 5;        // 32/64/128 — always even, >= 32
  const int W = KSTEPS >> 1;        // windows (16/32/64)
  const int KS1W = (Ksplit >> 5) >> 1;  // part-1 windows (even splits only)

  // ---- staging: one window = 2 k-steps x 16 KB = 8 DMAs/wave (1 KB each)
  const short* sAh = A1h;
  const short* sAl = A1l;
  const unsigned aBase0 = (unsigned)((blockM >> 4) * 512 + lane * 8);
  unsigned aOff = aBase0;
  int stageW = 0;
  auto stageNext = [&](short* dst) {
#pragma unroll
    for (int sub = 0; sub < 2; sub++) {
#pragma unroll
      for (int s = 0; s < 4; s++) {
        int g = s * 4 + wave;          // 0..15: chunk id (0-7 hi, 8-15 lo)
        const short* plane = (g < 8) ? sAh : sAl;
        gld_lds16(plane + aOff + sub * (MCH * 512) + (g & 7) * 512,
                  dst + sub * 8192 + g * 512);
      }
    }
    aOff += 2u * (MCH * 512);
    if (++stageW == KS1W) { sAh = A2h; sAl = A2l; aOff = aBase0; }
  };

  // ---- B-load state (8 x 16B loads per wave per K-step), 32-bit offset
  unsigned bOff = (unsigned)(((blockN >> 4) + wn * 4) * 512 + lane * 8);
  const unsigned bStride = (unsigned)N * 32;
  auto loadBNext = [&](f16x8 (&bH)[4], f16x8 (&bL)[4]) {
#pragma unroll
    for (int t = 0; t < 4; t++) bH[t] = *(const f16x8*)(BTh + bOff + t * 512);
#pragma unroll
    for (int t = 0; t < 4; t++) bL[t] = *(const f16x8*)(BTl + bOff + t * 512);
    bOff += bStride;
  };

  f16x8 b0H[4], b0L[4], b1H[4], b1L[4];

  // one K-sub-step: aH reads -> 32 MFMA -> aL reads -> 16 MFMA (staggered
  // aH/aL liveness caps arch VGPR)
  auto computeSub = [&](const short* buf, int sub, f16x8 (&bH)[4],
                        f16x8 (&bL)[4]) {
    f16x8 aH[4];
#pragma unroll
    for (int t = 0; t < 4; t++)
      aH[t] = *(const f16x8*)&buf[sub * 8192 + (wm * 4 + t) * 512 + lane * 8];
    __builtin_amdgcn_s_setprio(1);
#pragma unroll
    for (int i = 0; i < 4; i++)
#pragma unroll
      for (int j = 0; j < 4; j++)
        acc1[i][j] = __builtin_amdgcn_mfma_f32_16x16x32_f16(aH[i], bH[j],
                                                            acc1[i][j], 0, 0, 0);
#pragma unroll
    for (int i = 0; i < 4; i++)
#pragma unroll
      for (int j = 0; j < 4; j++)
        acc2[i][j] = __builtin_amdgcn_mfma_f32_16x16x32_f16(aH[i], bL[j],
                                                            acc2[i][j], 0, 0, 0);
    __builtin_amdgcn_s_setprio(0);
    f16x8 aL[4];
#pragma unroll
    for (int t = 0; t < 4; t++)
      aL[t] = *(const f16x8*)&buf[sub * 8192 + (8 + wm * 4 + t) * 512 +
                                  lane * 8];
    __builtin_amdgcn_s_setprio(1);
#pragma unroll
    for (int i = 0; i < 4; i++)
#pragma unroll
      for (int j = 0; j < 4; j++)
        acc2[i][j] = __builtin_amdgcn_mfma_f32_16x16x32_f16(aL[i], bH[j],
                                                            acc2[i][j], 0, 0, 0);
    __builtin_amdgcn_s_setprio(0);
  };

#define SB0 __builtin_amdgcn_sched_barrier(0)

  // ---- prologue: stage window 0 -> lds0; load B(0); publish lds0.
  stageNext(lds0);                   // S0: 8
  loadBNext(b0H, b0L);               // L(k0): 8  (16 outstanding)
  asm volatile("s_waitcnt vmcnt(8)" ::: "memory");  // S0 done; L(k0) flies
  __builtin_amdgcn_s_barrier();
  SB0;
  // invariant entering window w: outstanding [L(k0) 8]; buf[w] published

  short* cur = lds0;
  short* oth = lds1;
  for (int w = 0; w < W - 1; ++w) {
    loadBNext(b1H, b1L);             // L(k1): 8 -> 16
    stageNext(oth);                  // S(w+1): 8 -> 24 (other buffer; its
                                     // reads retired before last barrier)
    computeSub(cur, 0, b0H, b0L);    // auto vmcnt(16) before B(k0) use
    SB0;                             // pin: S issued before L(k2)
    loadBNext(b0H, b0L);             // L(k2): 8 (set0 consumed above)
    computeSub(cur, 1, b1H, b1L);    // auto vmcnt(16) before B(k1) use
    SB0;
    asm volatile("s_waitcnt vmcnt(8)" ::: "memory");  // retire S(w+1)
    __builtin_amdgcn_s_barrier();    // publish buf[w+1]; L(k2) crosses
    SB0;
    short* t = cur; cur = oth; oth = t;
  }

  // ---- tail window W-1: no stage, no L(k2); compiler auto-waits.
  loadBNext(b1H, b1L);
  computeSub(cur, 0, b0H, b0L);
  computeSub(cur, 1, b1H, b1L);

  // epilogue: combine accs, bias + per-column activation + clip.
  // C/D map col=lane&15, row=quad*4+reg (m89-verified).
  // OUT_F16 path writes PACKED layout (next layer's A): chunkrow=row>>4,
  // kstep=col>>5, lane'=((col>>3)&3)*16 + (row&15), j'=col&7.
#pragma unroll
  for (int j = 0; j < 4; j++) {
    int col = blockN + wn * 64 + j * 16 + m16;
    float b = bias[col];
    float m = mo[col];
    int a = aid[col];
    size_t kbase = OUT_F16 ? ((size_t)(col >> 5) * MCH) * 512 +
                                 (size_t)((col >> 3) & 3) * 128 + (col & 7)
                           : 0;
#pragma unroll
    for (int i = 0; i < 4; i++) {
#pragma unroll
      for (int r = 0; r < 4; r++) {
        int row = blockM + wm * 64 + i * 16 + quad * 4 + r;
        float s = acc1[i][j][r] + acc2[i][j][r] * INV_LO_SCALE;
        float v = rand_act(s + b, a, m);
        if (OUT_F16) {
          unsigned short h, l;
          split_h(v, h, l);
          size_t pidx = kbase + (size_t)(row >> 4) * 512 + (row & 15) * 8;
          Ch[pidx] = h;
          Cl[pidx] = l;
        } else {
          Cf[(size_t)row * N + col] = v;
        }
      }
    }
  }
}

extern "C" void kernel_launch(void* const* d_in, const int* in_sizes, int n_in,
                              void* d_out, int out_size, void* d_ws,
                              size_t ws_size, hipStream_t stream) {
  (void)in_sizes; (void)n_in; (void)out_size; (void)ws_size;

  const float* x     = (const float*)d_in[0];
  const float* W_in  = (const float*)d_in[1];
  const float* b_in  = (const float*)d_in[2];
  const float* Wh[6] = {(const float*)d_in[3], (const float*)d_in[4],
                        (const float*)d_in[5], (const float*)d_in[6],
                        (const float*)d_in[7], (const float*)d_in[8]};
  const float* bh    = (const float*)d_in[9];
  const float* W_out = (const float*)d_in[10];
  const float* b_out = (const float*)d_in[11];
  const float* mo_in = (const float*)d_in[12];
  const float* mo_h  = (const float*)d_in[13];
  const float* mo_out= (const float*)d_in[14];
  const int* aid_in  = (const int*)d_in[15];
  const int* aid_h   = (const int*)d_in[16];
  const int* aid_out = (const int*)d_in[17];

  const int hin[6] = {XDIM, XDIM, 2 * XDIM, XDIM, 2 * XDIM, XDIM};

  // workspace layout (~264 MB); each tensor = hi plane then lo plane (packed)
  char* p = (char*)d_ws;
  auto take = [&](size_t elems) {
    short* q = (short*)p;
    p += elems * 2 * 2;  // hi + lo, 2B each
    return q;
  };
  short* x_s = take((size_t)BDIM * INDIM);
  size_t xpl = (size_t)BDIM * INDIM;
  short* w_in_s = take((size_t)XDIM * INDIM);
  size_t wpl_in = (size_t)XDIM * INDIM;
  short* w_h_s[6];
  size_t wpl_h[6];
  for (int i = 0; i < 6; i++) {
    wpl_h[i] = (size_t)XDIM * hin[i];
    w_h_s[i] = take(wpl_h[i]);
  }
  short* w_out_s = take((size_t)OUTDIM * XDIM);
  size_t wpl_out = (size_t)OUTDIM * XDIM;
  const size_t apl = (size_t)BDIM * XDIM;  // activation plane
  short* actA = take(apl);
  short* actB = take(apl);
  short* actC = take(apl);

  // 1) pack x -> hi/lo fp16 packed
  pack_x<<<dim3(INDIM / 32, BDIM / 64), dim3(256), 0, stream>>>(
      x, (unsigned short*)x_s, (unsigned short*)(x_s + xpl), INDIM);
  // 2) pack all weights: W(K,N) -> packed BT(rows=N, Kdim=K) hi/lo
  pack_w<<<dim3(XDIM / 32, INDIM / 32), dim3(32, 8), 0, stream>>>(
      W_in, (unsigned short*)w_in_s, (unsigned short*)(w_in_s + wpl_in), INDIM,
      XDIM);
  for (int i = 0; i < 6; i++)
    pack_w<<<dim3(XDIM / 32, hin[i] / 32), dim3(32, 8), 0, stream>>>(
        Wh[i], (unsigned short*)w_h_s[i],
        (unsigned short*)(w_h_s[i] + wpl_h[i]), hin[i], XDIM);
  pack_w<<<dim3(OUTDIM / 32, XDIM / 32), dim3(32, 8), 0, stream>>>(
      W_out, (unsigned short*)w_out_s, (unsigned short*)(w_out_s + wpl_out),
      XDIM, OUTDIM);

  // 3) GEMM chain with 3 rotating activation buffers
  auto G = [&](const short* A1, size_t a1pl, const short* A2, size_t a2pl,
               const short* W, size_t wpl, const float* bi, const float* m,
               const int* a, short* Cb, float* Cf, int N, int K, int Ks) {
    dim3 grid(N / 128, BDIM / 128);
    const short* A2h = A2;
    const short* A2l = A2 ? A2 + a2pl : nullptr;
    if (Cb)
      gemm_split_act<true><<<grid, 256, 0, stream>>>(
          A1, A1 + a1pl, A2h, A2l, W, W + wpl, bi, m, a, (unsigned short*)Cb,
          (unsigned short*)(Cb + apl), nullptr, N, K, Ks);
    else
      gemm_split_act<false><<<grid, 256, 0, stream>>>(
          A1, A1 + a1pl, A2h, A2l, W, W + wpl, bi, m, a, nullptr, nullptr, Cf,
          N, K, Ks);
  };

  // input layer: outs[0]=actA
  G(x_s, xpl, nullptr, 0, w_in_s, wpl_in, b_in, mo_in, aid_in, actA, nullptr,
    XDIM, INDIM, INDIM);
  // L0: outs[1]=actB
  G(actA, apl, nullptr, 0, w_h_s[0], wpl_h[0], bh + 0 * XDIM, mo_h + 0 * XDIM,
    aid_h + 0 * XDIM, actB, nullptr, XDIM, XDIM, XDIM);
  // L1: outs[2]=actC
  G(actB, apl, nullptr, 0, w_h_s[1], wpl_h[1], bh + 1 * XDIM, mo_h + 1 * XDIM,
    aid_h + 1 * XDIM, actC, nullptr, XDIM, XDIM, XDIM);
  // L2 (concat outs2,outs1): outs[3]=actA
  G(actC, apl, actB, apl, w_h_s[2], wpl_h[2], bh + 2 * XDIM, mo_h + 2 * XDIM,
    aid_h + 2 * XDIM, actA, nullptr, XDIM, 2 * XDIM, XDIM);
  // L3: outs[4]=actB
  G(actA, apl, nullptr, 0, w_h_s[3], wpl_h[3], bh + 3 * XDIM, mo_h + 3 * XDIM,
    aid_h + 3 * XDIM, actB, nullptr, XDIM, XDIM, XDIM);
  // L4 (concat outs4,outs3): outs[5]=actC
  G(actB, apl, actA, apl, w_h_s[4], wpl_h[4], bh + 4 * XDIM, mo_h + 4 * XDIM,
    aid_h + 4 * XDIM, actC, nullptr, XDIM, 2 * XDIM, XDIM);
  // L5: outs[6]=actB
  G(actC, apl, nullptr, 0, w_h_s[5], wpl_h[5], bh + 5 * XDIM, mo_h + 5 * XDIM,
    aid_h + 5 * XDIM, actB, nullptr, XDIM, XDIM, XDIM);
  // output layer -> d_out (fp32, row-major)
  G(actB, apl, nullptr, 0, w_out_s, wpl_out, b_out, mo_out, aid_out, nullptr,
    (float*)d_out, OUTDIM, XDIM, XDIM);
}

// Round 6
// 1333.978 us; speedup vs baseline: 1.0107x; 1.0107x over previous
//
#include <hip/hip_runtime.h>
#include <stdint.h>
#include <string.h>

// Problem dims (fixed by the reference)
#define BDIM   4096
#define INDIM  1024
#define XDIM   2048
#define OUTDIM 512
#define MCH    (BDIM / 16)   // 256 row-chunks along M for packed activations

#define LO_SCALE 2048.0f         // 2^11: lifts fp16 lo-plane out of subnormals
#define INV_LO_SCALE (1.0f / 2048.0f)

typedef _Float16 f16x8 __attribute__((ext_vector_type(8)));
typedef float f32x16 __attribute__((ext_vector_type(16)));
typedef unsigned short u16x8 __attribute__((ext_vector_type(8)));
typedef unsigned short u16x4 __attribute__((ext_vector_type(4)));

__device__ __forceinline__ unsigned short h2u(_Float16 h) {
  unsigned short u;
  memcpy(&u, &h, 2);
  return u;
}

// split f32 into hi fp16 + scaled-lo fp16 (combined ~22 mantissa bits).
// Scale 2^11 keeps residuals out of f16-subnormal range (MFMA denorm
// behavior unverified — don't gamble).
__device__ __forceinline__ void split_h(float v, unsigned short& h,
                                        unsigned short& l) {
  _Float16 hh = (_Float16)v;                       // RTNE
  float r = v - (float)hh;                         // exact
  _Float16 ll = (_Float16)(r * LO_SCALE);          // |r|*2^11 <= |v|, no inf
  h = h2u(hh);
  l = h2u(ll);
}

// async global->LDS, 16B per lane; LDS dest wave-uniform base + lane*16
__device__ __forceinline__ void gld_lds16(const void* g, void* l) {
  __builtin_amdgcn_global_load_lds(
      (const __attribute__((address_space(1))) uint32_t*)g,
      (__attribute__((address_space(3))) uint32_t*)l, 16, 0, 0);
}

// fused RandomActivation + clip (relu/sigmoid/tanh/leaky(.1)/selu), libm-grade
__device__ __forceinline__ float rand_act(float v, int a, float mo) {
  float r;
  if (a == 0) {
    r = fmaxf(v, 0.0f);
  } else if (a == 1) {
    r = 1.0f / (1.0f + expf(-v));
  } else if (a == 2) {
    r = tanhf(v);
  } else if (a == 3) {
    r = (v >= 0.0f) ? v : 0.1f * v;
  } else {  // selu (matches jax: scale * where(v>0, v, alpha*expm1(v)))
    r = (v > 0.0f) ? 1.0507009873554805f * v
                   : 1.7580993408473766f * expm1f(v);
  }
  return fminf(r, mo);
}

// ---------------------------------------------------------------------------
// PACKED LAYOUT: tensor X[rows][K] is stored as
//   packed[k/32][row/16][lane(64)][8 halfs],
// lane = quad*16 + m16 holding X[chunkrow*16 + m16][kstep*32 + quad*8 + j].
// Each (kstep,chunk) = contiguous 1 KB: staging DMA is consecutive-lane-
// contiguous AND compute reads are contiguous (zero conflicts).
// Concat along K = packed tensors back-to-back.
// ---------------------------------------------------------------------------

// x[BDIM][Kin] f32 row-major -> packed hi/lo planes. grid(Kin/32, BDIM/64)x256
__global__ void pack_x(const float* __restrict__ s,
                       unsigned short* __restrict__ dh,
                       unsigned short* __restrict__ dl, int Kin) {
  int ks = blockIdx.x;
  int mblk = blockIdx.y;
  int cc = threadIdx.x >> 6;        // chunk within 64-row group
  int lane = threadIdx.x & 63;
  int m16 = lane & 15, quad = lane >> 4;
  int row = mblk * 64 + cc * 16 + m16;
  const float* src = s + (size_t)row * Kin + ks * 32 + quad * 8;
  size_t o = ((size_t)ks * MCH + mblk * 4 + cc) * 512 + lane * 8;
  float4 v0 = *(const float4*)src;
  float4 v1 = *(const float4*)(src + 4);
  float vs[8] = {v0.x, v0.y, v0.z, v0.w, v1.x, v1.y, v1.z, v1.w};
  u16x8 vh, vl;
#pragma unroll
  for (int j = 0; j < 8; j++) {
    unsigned short h, l;
    split_h(vs[j], h, l);
    vh[j] = h;
    vl[j] = l;
  }
  *(u16x8*)(dh + o) = vh;
  *(u16x8*)(dl + o) = vl;
}

// W[K][N] f32 row-major -> packed-BT hi/lo (rows=N, Kdim=K).
// grid(N/32, K/32), block(32,8).
__global__ void pack_w(const float* __restrict__ W,
                       unsigned short* __restrict__ dh,
                       unsigned short* __restrict__ dl, int K, int N) {
  __shared__ float t[32][33];       // t[k'][n']
  int n0 = blockIdx.x * 32, k0 = blockIdx.y * 32;
  int tx = threadIdx.x, ty = threadIdx.y;
#pragma unroll
  for (int i = 0; i < 32; i += 8)
    t[ty + i][tx] = W[(size_t)(k0 + ty + i) * N + n0 + tx];
  __syncthreads();
  int tt = ty * 32 + tx;            // 0..255
  int ci = tt >> 7;                 // n-chunk 0/1
  int rem = tt & 127;
  int lane = rem >> 1;
  int j4 = (rem & 1) * 4;
  int m16 = lane & 15, quad = lane >> 4;
  size_t o = ((size_t)(k0 >> 5) * (N >> 4) + (n0 >> 4) + ci) * 512 +
             lane * 8 + j4;
  u16x4 vh, vl;
#pragma unroll
  for (int jj = 0; jj < 4; jj++) {
    float v = t[quad * 8 + j4 + jj][ci * 16 + m16];
    unsigned short h, l;
    split_h(v, h, l);
    vh[jj] = h;
    vl[jj] = l;
  }
  *(u16x4*)(dh + o) = vh;
  *(u16x4*)(dl + o) = vl;
}

// C[M,N] = act( A[M,K] @ BT[N,K]^T + bias ), split-fp16 (3-term) precision.
// acc1 = hi*hi; acc2 = hi*lo' + lo'*hi at scale 2^11. Final = acc1+acc2/2^11.
//
// Round-15 structure (R5 resubmit, numerics hardened back to proven form):
//  - MFMA 32x32x16_f16: 12 instr/K-step/wave (was 24 of 16x16x32), f16 pipe
//    ceiling 1955->2178 TF. A/B share identical packed fragment geometry so
//    any k-permutation cancels (A/B symmetric); C/D: col=lane&31,
//    row=(reg&3)+8*(reg>>2)+4*(lane>>5) (m74/m101-verified).
//  - SCALED lo plane + dual acc (proven R0-R4 numerics): acc1/acc2 =
//    2 x f32x16 each tile pair = 64 AGPR; arch VGPR target <= 64 ->
//    128 unified -> 4 waves/SIMD (R3-proven occupancy).
//  - A-frag addresses fold into read offset immediates (one addr reg).
//  - Schedule/ledger = R3's counted-vmcnt single-barrier window; pre-barrier
//    wait vmcnt(4) (actually retires the stage DMAs).
// Block tile 64x128, 4 waves (wave-tile 64x32), window = 2 K-steps.
// Grid (N/128, M/64) = 1024 blocks = exactly 4/CU. Linear block order.
template <bool OUT_F16>
__global__ __launch_bounds__(256, 4) void gemm_split_act(
    const short* __restrict__ A1h, const short* __restrict__ A1l,
    const short* __restrict__ A2h, const short* __restrict__ A2l,
    const short* __restrict__ BTh, const short* __restrict__ BTl,
    const float* __restrict__ bias, const float* __restrict__ mo,
    const int* __restrict__ aid, unsigned short* __restrict__ Ch,
    unsigned short* __restrict__ Cl, float* __restrict__ Cf, int N, int K,
    int Ksplit) {
  __shared__ short lds0[2 * 8 * 512];   // 16 KB: [sub][8 chunks][512]
  __shared__ short lds1[2 * 8 * 512];   // chunks 0-3 hi rows 0-63, 4-7 lo

  const int tid = threadIdx.x;
  const int lane = tid & 63;
  const int wave = tid >> 6;        // 0..3 = 32-col n-strip of wave
  const int m16 = lane & 15;

  const int blockN = blockIdx.x * 128;   // linear order (proven locality)
  const int blockM = blockIdx.y * 64;

  // per-lane fragment sub-offset (halfs) for 32x32x16:
  // element (row=l&31, k=8*(l>>5)+j), k-half s adds 256.
  // chunk select ((l>>4)&1)*512; within chunk (s*2+(l>>5))*128 + (l&15)*8.
  const int laneA = ((lane >> 4) & 1) * 512 + (lane >> 5) * 128 + m16 * 8;

  f32x16 acc1[2];  // hi*hi           (per 32-row M-tile)
  f32x16 acc2[2];  // hi*lo' + lo'*hi (scale 2^11)
  acc1[0] = (f32x16)(0.0f);
  acc1[1] = (f32x16)(0.0f);
  acc2[0] = (f32x16)(0.0f);
  acc2[1] = (f32x16)(0.0f);

  const int KSTEPS = K >> 5;        // 32/64/128 — always even, >= 32
  const int W = KSTEPS >> 1;        // windows (16/32/64)
  const int KS1W = (Ksplit >> 5) >> 1;  // part-1 windows (even splits only)

  // ---- staging: one window = 2 k-steps = 4 DMAs/wave (1 KB each)
  const short* sAh = A1h;
  const short* sAl = A1l;
  const unsigned aBase0 = (unsigned)((blockM >> 4) * 512 + lane * 8);
  unsigned aOff = aBase0;
  int stageW = 0;
  auto stageNext = [&](short* dst) {
#pragma unroll
    for (int sub = 0; sub < 2; sub++) {
#pragma unroll
      for (int s = 0; s < 2; s++) {
        int g = wave * 2 + s;          // 0..7
        const short* plane = (g < 4) ? sAh : sAl;
        gld_lds16(plane + aOff + sub * (MCH * 512) + (g & 3) * 512,
                  dst + sub * 4096 + g * 512);
      }
    }
    aOff += 2u * (MCH * 512);
    if (++stageW == KS1W) { sAh = A2h; sAl = A2l; aOff = aBase0; }
  };

  // ---- B-load state (4 x 16B loads per wave per K-step), 32-bit offset
  const short* BThL = BTh + laneA;   // same fragment geometry as A
  const short* BTlL = BTl + laneA;
  unsigned bOff = (unsigned)(((blockN >> 4) + wave * 2) * 512);
  const unsigned bStride = (unsigned)N * 32;
  auto loadBNext = [&](f16x8 (&bH)[2], f16x8 (&bL)[2]) {
    bH[0] = *(const f16x8*)(BThL + bOff);
    bH[1] = *(const f16x8*)(BThL + bOff + 256);
    bL[0] = *(const f16x8*)(BTlL + bOff);
    bL[1] = *(const f16x8*)(BTlL + bOff + 256);
    bOff += bStride;
  };

  f16x8 b0H[2], b0L[2], b1H[2], b1L[2];

  // one K-sub-step: 12 x mfma_32x32x16 (3-term), staggered aH/aL liveness
  auto computeSub = [&](const short* buf, int sub, f16x8 (&bH)[2],
                        f16x8 (&bL)[2]) {
    const short* p = buf + sub * 4096 + laneA;
    f16x8 aH[4];  // [mi*2+s]
#pragma unroll
    for (int mi = 0; mi < 2; mi++)
#pragma unroll
      for (int s = 0; s < 2; s++)
        aH[mi * 2 + s] = *(const f16x8*)(p + mi * 1024 + s * 256);
    __builtin_amdgcn_s_setprio(1);
#pragma unroll
    for (int s = 0; s < 2; s++)
#pragma unroll
      for (int mi = 0; mi < 2; mi++)
        acc1[mi] = __builtin_amdgcn_mfma_f32_32x32x16_f16(aH[mi * 2 + s],
                                                          bH[s], acc1[mi],
                                                          0, 0, 0);
#pragma unroll
    for (int s = 0; s < 2; s++)
#pragma unroll
      for (int mi = 0; mi < 2; mi++)
        acc2[mi] = __builtin_amdgcn_mfma_f32_32x32x16_f16(aH[mi * 2 + s],
                                                          bL[s], acc2[mi],
                                                          0, 0, 0);
    __builtin_amdgcn_s_setprio(0);
    f16x8 aL[4];
#pragma unroll
    for (int mi = 0; mi < 2; mi++)
#pragma unroll
      for (int s = 0; s < 2; s++)
        aL[mi * 2 + s] = *(const f16x8*)(p + 2048 + mi * 1024 + s * 256);
    __builtin_amdgcn_s_setprio(1);
#pragma unroll
    for (int s = 0; s < 2; s++)
#pragma unroll
      for (int mi = 0; mi < 2; mi++)
        acc2[mi] = __builtin_amdgcn_mfma_f32_32x32x16_f16(aL[mi * 2 + s],
                                                          bH[s], acc2[mi],
                                                          0, 0, 0);
    __builtin_amdgcn_s_setprio(0);
  };

#define SB0 __builtin_amdgcn_sched_barrier(0)

  // ---- prologue: stage window 0 -> lds0; load B(0); publish lds0.
  stageNext(lds0);                   // S0: 4  (FIFO-oldest)
  loadBNext(b0H, b0L);               // L(k0): 4  (8 outstanding)
  asm volatile("s_waitcnt vmcnt(4)" ::: "memory");  // retires S0; L(k0) flies
  __builtin_amdgcn_s_barrier();
  SB0;
  // invariant entering window w: outstanding [L(k0) 4]; buf[w] published

  short* cur = lds0;
  short* oth = lds1;
  for (int w = 0; w < W - 1; ++w) {
    loadBNext(b1H, b1L);             // L(k1): 4 -> 8
    stageNext(oth);                  // S(w+1): 4 -> 12
    computeSub(cur, 0, b0H, b0L);    // auto-wait retires L(k0)
    SB0;                             // pin: S issued before L(k2)
    loadBNext(b0H, b0L);             // L(k2): 4
    computeSub(cur, 1, b1H, b1L);    // auto-wait retires L(k1)
    SB0;
    asm volatile("s_waitcnt vmcnt(4)" ::: "memory");  // retires S(w+1)
    __builtin_amdgcn_s_barrier();    // publish buf[w+1]; L(k2) crosses
    SB0;
    short* t = cur; cur = oth; oth = t;
  }

  // ---- tail window W-1: no stage, no L(k2); compiler auto-waits.
  loadBNext(b1H, b1L);
  computeSub(cur, 0, b0H, b0L);
  computeSub(cur, 1, b1H, b1L);

  // epilogue: combine accs, bias + per-column activation + clip.
  // C/D 32x32 map: col=lane&31, row=(reg&3)+8*(reg>>2)+4*(lane>>5).
  // OUT_F16 writes PACKED layout (next layer's A).
  {
    const int col = blockN + wave * 32 + (lane & 31);
    const float b = bias[col];
    const float m = mo[col];
    const int a = aid[col];
    const size_t kbase =
        OUT_F16 ? (size_t)(col >> 5) * MCH * 512 +
                      (size_t)((col >> 3) & 3) * 128 + (col & 7)
                : 0;
#pragma unroll
    for (int mi = 0; mi < 2; mi++) {
      const int rbase = blockM + mi * 32 + 4 * (lane >> 5);
#pragma unroll
      for (int r = 0; r < 16; r++) {
        const int row = rbase + (r & 3) + 8 * (r >> 2);
        const float s = acc1[mi][r] + acc2[mi][r] * INV_LO_SCALE;
        const float v = rand_act(s + b, a, m);
        if (OUT_F16) {
          unsigned short h, l;
          split_h(v, h, l);
          size_t pidx = kbase + (size_t)(row >> 4) * 512 + (row & 15) * 8;
          Ch[pidx] = h;
          Cl[pidx] = l;
        } else {
          Cf[(size_t)row * N + col] = v;
        }
      }
    }
  }
}

extern "C" void kernel_launch(void* const* d_in, const int* in_sizes, int n_in,
                              void* d_out, int out_size, void* d_ws,
                              size_t ws_size, hipStream_t stream) {
  (void)in_sizes; (void)n_in; (void)out_size; (void)ws_size;

  const float* x     = (const float*)d_in[0];
  const float* W_in  = (const float*)d_in[1];
  const float* b_in  = (const float*)d_in[2];
  const float* Wh[6] = {(const float*)d_in[3], (const float*)d_in[4],
                        (const float*)d_in[5], (const float*)d_in[6],
                        (const float*)d_in[7], (const float*)d_in[8]};
  const float* bh    = (const float*)d_in[9];
  const float* W_out = (const float*)d_in[10];
  const float* b_out = (const float*)d_in[11];
  const float* mo_in = (const float*)d_in[12];
  const float* mo_h  = (const float*)d_in[13];
  const float* mo_out= (const float*)d_in[14];
  const int* aid_in  = (const int*)d_in[15];
  const int* aid_h   = (const int*)d_in[16];
  const int* aid_out = (const int*)d_in[17];

  const int hin[6] = {XDIM, XDIM, 2 * XDIM, XDIM, 2 * XDIM, XDIM};

  // workspace layout (~264 MB); each tensor = hi plane then lo plane (packed)
  char* p = (char*)d_ws;
  auto take = [&](size_t elems) {
    short* q = (short*)p;
    p += elems * 2 * 2;  // hi + lo, 2B each
    return q;
  };
  short* x_s = take((size_t)BDIM * INDIM);
  size_t xpl = (size_t)BDIM * INDIM;
  short* w_in_s = take((size_t)XDIM * INDIM);
  size_t wpl_in = (size_t)XDIM * INDIM;
  short* w_h_s[6];
  size_t wpl_h[6];
  for (int i = 0; i < 6; i++) {
    wpl_h[i] = (size_t)XDIM * hin[i];
    w_h_s[i] = take(wpl_h[i]);
  }
  short* w_out_s = take((size_t)OUTDIM * XDIM);
  size_t wpl_out = (size_t)OUTDIM * XDIM;
  const size_t apl = (size_t)BDIM * XDIM;  // activation plane
  short* actA = take(apl);
  short* actB = take(apl);
  short* actC = take(apl);

  // 1) pack x -> hi/lo fp16 packed
  pack_x<<<dim3(INDIM / 32, BDIM / 64), dim3(256), 0, stream>>>(
      x, (unsigned short*)x_s, (unsigned short*)(x_s + xpl), INDIM);
  // 2) pack all weights: W(K,N) -> packed BT(rows=N, Kdim=K) hi/lo
  pack_w<<<dim3(XDIM / 32, INDIM / 32), dim3(32, 8), 0, stream>>>(
      W_in, (unsigned short*)w_in_s, (unsigned short*)(w_in_s + wpl_in), INDIM,
      XDIM);
  for (int i = 0; i < 6; i++)
    pack_w<<<dim3(XDIM / 32, hin[i] / 32), dim3(32, 8), 0, stream>>>(
        Wh[i], (unsigned short*)w_h_s[i],
        (unsigned short*)(w_h_s[i] + wpl_h[i]), hin[i], XDIM);
  pack_w<<<dim3(OUTDIM / 32, XDIM / 32), dim3(32, 8), 0, stream>>>(
      W_out, (unsigned short*)w_out_s, (unsigned short*)(w_out_s + wpl_out),
      XDIM, OUTDIM);

  // 3) GEMM chain with 3 rotating activation buffers
  auto G = [&](const short* A1, size_t a1pl, const short* A2, size_t a2pl,
               const short* W, size_t wpl, const float* bi, const float* m,
               const int* a, short* Cb, float* Cf, int N, int K, int Ks) {
    dim3 grid(N / 128, BDIM / 64);
    const short* A2h = A2;
    const short* A2l = A2 ? A2 + a2pl : nullptr;
    if (Cb)
      gemm_split_act<true><<<grid, 256, 0, stream>>>(
          A1, A1 + a1pl, A2h, A2l, W, W + wpl, bi, m, a, (unsigned short*)Cb,
          (unsigned short*)(Cb + apl), nullptr, N, K, Ks);
    else
      gemm_split_act<false><<<grid, 256, 0, stream>>>(
          A1, A1 + a1pl, A2h, A2l, W, W + wpl, bi, m, a, nullptr, nullptr, Cf,
          N, K, Ks);
  };

  // input layer: outs[0]=actA
  G(x_s, xpl, nullptr, 0, w_in_s, wpl_in, b_in, mo_in, aid_in, actA, nullptr,
    XDIM, INDIM, INDIM);
  // L0: outs[1]=actB
  G(actA, apl, nullptr, 0, w_h_s[0], wpl_h[0], bh + 0 * XDIM, mo_h + 0 * XDIM,
    aid_h + 0 * XDIM, actB, nullptr, XDIM, XDIM, XDIM);
  // L1: outs[2]=actC
  G(actB, apl, nullptr, 0, w_h_s[1], wpl_h[1], bh + 1 * XDIM, mo_h + 1 * XDIM,
    aid_h + 1 * XDIM, actC, nullptr, XDIM, XDIM, XDIM);
  // L2 (concat outs2,outs1): outs[3]=actA
  G(actC, apl, actB, apl, w_h_s[2], wpl_h[2], bh + 2 * XDIM, mo_h + 2 * XDIM,
    aid_h + 2 * XDIM, actA, nullptr, XDIM, 2 * XDIM, XDIM);
  // L3: outs[4]=actB
  G(actA, apl, nullptr, 0, w_h_s[3], wpl_h[3], bh + 3 * XDIM, mo_h + 3 * XDIM,
    aid_h + 3 * XDIM, actB, nullptr, XDIM, XDIM, XDIM);
  // L4 (concat outs4,outs3): outs[5]=actC
  G(actB, apl, actA, apl, w_h_s[4], wpl_h[4], bh + 4 * XDIM, mo_h + 4 * XDIM,
    aid_h + 4 * XDIM, actC, nullptr, XDIM, 2 * XDIM, XDIM);
  // L5: outs[6]=actB
  G(actC, apl, nullptr, 0, w_h_s[5], wpl_h[5], bh + 5 * XDIM, mo_h + 5 * XDIM,
    aid_h + 5 * XDIM, actB, nullptr, XDIM, XDIM, XDIM);
  // output layer -> d_out (fp32, row-major)
  G(actB, apl, nullptr, 0, w_out_s, wpl_out, b_out, mo_out, aid_out, nullptr,
    (float*)d_out, OUTDIM, XDIM, XDIM);
}

// Round 7
// 1116.434 us; speedup vs baseline: 1.2077x; 1.1949x over previous
//
#include <hip/hip_runtime.h>
#include <stdint.h>
#include <string.h>

// Problem dims (fixed by the reference)
#define BDIM   4096
#define INDIM  1024
#define XDIM   2048
#define OUTDIM 512
#define MCH    (BDIM / 16)   // 256 row-chunks along M for packed activations

#define LO_SCALE 2048.0f         // 2^11: lifts fp16 lo-plane out of subnormals
#define INV_LO_SCALE (1.0f / 2048.0f)

typedef _Float16 f16x8 __attribute__((ext_vector_type(8)));
typedef float f32x4 __attribute__((ext_vector_type(4)));
typedef unsigned short u16x8 __attribute__((ext_vector_type(8)));
typedef unsigned short u16x4 __attribute__((ext_vector_type(4)));

__device__ __forceinline__ unsigned short h2u(_Float16 h) {
  unsigned short u;
  memcpy(&u, &h, 2);
  return u;
}

// split f32 into hi fp16 + scaled-lo fp16 (combined ~22 mantissa bits)
__device__ __forceinline__ void split_h(float v, unsigned short& h,
                                        unsigned short& l) {
  _Float16 hh = (_Float16)v;                       // RTNE
  float r = v - (float)hh;                         // exact
  _Float16 ll = (_Float16)(r * LO_SCALE);          // |r|*2^11 <= |v|, no inf
  h = h2u(hh);
  l = h2u(ll);
}

// async global->LDS, 16B per lane; LDS dest wave-uniform base + lane*16
__device__ __forceinline__ void gld_lds16(const void* g, void* l) {
  __builtin_amdgcn_global_load_lds(
      (const __attribute__((address_space(1))) uint32_t*)g,
      (__attribute__((address_space(3))) uint32_t*)l, 16, 0, 0);
}

// fused RandomActivation + clip (relu/sigmoid/tanh/leaky(.1)/selu), libm-grade
__device__ __forceinline__ float rand_act(float v, int a, float mo) {
  float r;
  if (a == 0) {
    r = fmaxf(v, 0.0f);
  } else if (a == 1) {
    r = 1.0f / (1.0f + expf(-v));
  } else if (a == 2) {
    r = tanhf(v);
  } else if (a == 3) {
    r = (v >= 0.0f) ? v : 0.1f * v;
  } else {  // selu (matches jax: scale * where(v>0, v, alpha*expm1(v)))
    r = (v > 0.0f) ? 1.0507009873554805f * v
                   : 1.7580993408473766f * expm1f(v);
  }
  return fminf(r, mo);
}

// ---------------------------------------------------------------------------
// PACKED LAYOUT: tensor X[rows][K] is stored as
//   packed[k/32][row/16][lane(64)][8 halfs],
// lane = quad*16 + m16 holding X[chunkrow*16 + m16][kstep*32 + quad*8 + j].
// Each (kstep,chunk) = contiguous 1 KB: staging DMA is consecutive-lane-
// contiguous AND compute ds_read_b128 is contiguous (zero conflicts).
// Concat along K = packed tensors back-to-back.
// ---------------------------------------------------------------------------

// x[BDIM][Kin] f32 row-major -> packed hi/lo planes. grid(Kin/32, BDIM/64)x256
__global__ void pack_x(const float* __restrict__ s,
                       unsigned short* __restrict__ dh,
                       unsigned short* __restrict__ dl, int Kin) {
  int ks = blockIdx.x;
  int mblk = blockIdx.y;
  int cc = threadIdx.x >> 6;        // chunk within 64-row group
  int lane = threadIdx.x & 63;
  int m16 = lane & 15, quad = lane >> 4;
  int row = mblk * 64 + cc * 16 + m16;
  const float* src = s + (size_t)row * Kin + ks * 32 + quad * 8;
  size_t o = ((size_t)ks * MCH + mblk * 4 + cc) * 512 + lane * 8;
  float4 v0 = *(const float4*)src;
  float4 v1 = *(const float4*)(src + 4);
  float vs[8] = {v0.x, v0.y, v0.z, v0.w, v1.x, v1.y, v1.z, v1.w};
  u16x8 vh, vl;
#pragma unroll
  for (int j = 0; j < 8; j++) {
    unsigned short h, l;
    split_h(vs[j], h, l);
    vh[j] = h;
    vl[j] = l;
  }
  *(u16x8*)(dh + o) = vh;
  *(u16x8*)(dl + o) = vl;
}

// W[K][N] f32 row-major -> packed-BT hi/lo (rows=N, Kdim=K).
// grid(N/32, K/32), block(32,8).
__global__ void pack_w(const float* __restrict__ W,
                       unsigned short* __restrict__ dh,
                       unsigned short* __restrict__ dl, int K, int N) {
  __shared__ float t[32][33];       // t[k'][n']
  int n0 = blockIdx.x * 32, k0 = blockIdx.y * 32;
  int tx = threadIdx.x, ty = threadIdx.y;
#pragma unroll
  for (int i = 0; i < 32; i += 8)
    t[ty + i][tx] = W[(size_t)(k0 + ty + i) * N + n0 + tx];
  __syncthreads();
  int tt = ty * 32 + tx;            // 0..255
  int ci = tt >> 7;                 // n-chunk 0/1
  int rem = tt & 127;
  int lane = rem >> 1;
  int j4 = (rem & 1) * 4;
  int m16 = lane & 15, quad = lane >> 4;
  size_t o = ((size_t)(k0 >> 5) * (N >> 4) + (n0 >> 4) + ci) * 512 +
             lane * 8 + j4;
  u16x4 vh, vl;
#pragma unroll
  for (int jj = 0; jj < 4; jj++) {
    float v = t[quad * 8 + j4 + jj][ci * 16 + m16];
    unsigned short h, l;
    split_h(v, h, l);
    vh[jj] = h;
    vl[jj] = l;
  }
  *(u16x4*)(dh + o) = vh;
  *(u16x4*)(dl + o) = vl;
}

// C[M,N] = act( A[M,K] @ BT[N,K]^T + bias ), split-fp16 (3-term) precision.
// acc1 = hi*hi; acc2 = hi*lo' + lo'*hi at scale 2^11. Final = acc1+acc2/2^11.
//
// Round-16 = Round-3 structure verbatim (best verified: 197.8 us hot,
// MfmaUtil 46%) + NT template for narrow-N layers:
//  - NT = per-wave n-tiles. NT=2: block 64x128 (all N=2048 layers, grid
//    1024 = 4 blocks/CU). NT=1: block 64x64 for the OUTPUT layer (N=512):
//    grid (8,64)=512 = 2 blocks/CU (was 256 = 1/CU = 1 wave/SIMD, the worst
//    occupancy of the chain). acc 32 AGPR, B-loads 2/K-step.
//  - counted-vmcnt single-barrier window (2 K-steps), 2 LDS buffers;
//    ledger: prologue stage(4)+loadB(2NT) -> vmcnt(2NT) retires stage;
//    loop: loadB(k1) 2NT, stage(w+1) 4, compute sub0, loadB(k2) 2NT,
//    compute sub1, vmcnt(2NT) retires stage, s_barrier. Never drains to 0.
//  - arch VGPR <= 64 (unified file: 64 AGPR acc + 64 arch = 128 -> 4
//    waves/SIMD, the R2/R4-proven TLP requirement).
//  - linear block order (proven: FETCH ~330 MB, B re-reads L3-warm).
template <bool OUT_F16, int NT>
__global__ __launch_bounds__(256, 4) void gemm_split_act(
    const short* __restrict__ A1h, const short* __restrict__ A1l,
    const short* __restrict__ A2h, const short* __restrict__ A2l,
    const short* __restrict__ BTh, const short* __restrict__ BTl,
    const float* __restrict__ bias, const float* __restrict__ mo,
    const int* __restrict__ aid, unsigned short* __restrict__ Ch,
    unsigned short* __restrict__ Cl, float* __restrict__ Cf, int N, int K,
    int Ksplit) {
  __shared__ short lds0[2 * 8 * 512];   // 16 KB: [sub][8 chunks][512]
  __shared__ short lds1[2 * 8 * 512];   // chunks 0-3 hi rows 0-63, 4-7 lo

  const int tid = threadIdx.x;
  const int lane = tid & 63;
  const int wave = tid >> 6;        // 0..3 = n-strip of wave
  const int m16 = lane & 15, quad = lane >> 4;

  const int blockN = blockIdx.x * (NT * 64);  // linear order (proven)
  const int blockM = blockIdx.y * 64;

  f32x4 acc1[4][NT];  // hi*hi
  f32x4 acc2[4][NT];  // (hi*lo' + lo'*hi), scale 2^11
#pragma unroll
  for (int i = 0; i < 4; i++)
#pragma unroll
    for (int j = 0; j < NT; j++) {
      acc1[i][j] = (f32x4){0.f, 0.f, 0.f, 0.f};
      acc2[i][j] = (f32x4){0.f, 0.f, 0.f, 0.f};
    }

  const int KSTEPS = K >> 5;        // 32/64/128 — always even, >= 32
  const int W = KSTEPS >> 1;        // windows (16/32/64)
  const int KS1W = (Ksplit >> 5) >> 1;  // part-1 windows (even splits only)

  // ---- staging: one window = 2 k-steps = 4 DMAs/wave (1 KB each)
  const short* sAh = A1h;
  const short* sAl = A1l;
  const unsigned aBase0 = (unsigned)((blockM >> 4) * 512 + lane * 8);
  unsigned aOff = aBase0;
  int stageW = 0;
  auto stageNext = [&](short* dst) {
#pragma unroll
    for (int sub = 0; sub < 2; sub++) {
#pragma unroll
      for (int s = 0; s < 2; s++) {
        int g = wave * 2 + s;          // 0..7
        const short* plane = (g < 4) ? sAh : sAl;
        gld_lds16(plane + aOff + sub * (MCH * 512) + (g & 3) * 512,
                  dst + sub * 4096 + g * 512);
      }
    }
    aOff += 2u * (MCH * 512);
    if (++stageW == KS1W) { sAh = A2h; sAl = A2l; aOff = aBase0; }
  };

  // ---- B-load state (2*NT x 16B loads per wave per K-step), 32-bit offset
  unsigned bOff = (unsigned)(((blockN >> 4) + wave * NT) * 512 + lane * 8);
  const unsigned bStride = (unsigned)N * 32;
  auto loadBNext = [&](f16x8 (&bH)[NT], f16x8 (&bL)[NT]) {
#pragma unroll
    for (int t = 0; t < NT; t++) {
      bH[t] = *(const f16x8*)(BTh + bOff + t * 512);
      bL[t] = *(const f16x8*)(BTl + bOff + t * 512);
    }
    bOff += bStride;
  };

  f16x8 aH[4], aL[4];               // single A-frag set
  f16x8 b0H[NT], b0L[NT], b1H[NT], b1L[NT];

  // one K-sub-step: aH reads -> 8NT MFMA -> aL reads -> 4NT MFMA (staggered
  // liveness keeps arch VGPR <= 64)
  auto computeSub = [&](const short* buf, int sub, f16x8 (&bH)[NT],
                        f16x8 (&bL)[NT]) {
#pragma unroll
    for (int t = 0; t < 4; t++)
      aH[t] = *(const f16x8*)&buf[sub * 4096 + t * 512 + lane * 8];
    __builtin_amdgcn_s_setprio(1);
#pragma unroll
    for (int i = 0; i < 4; i++)
#pragma unroll
      for (int j = 0; j < NT; j++)
        acc1[i][j] = __builtin_amdgcn_mfma_f32_16x16x32_f16(aH[i], bH[j],
                                                            acc1[i][j], 0, 0, 0);
#pragma unroll
    for (int i = 0; i < 4; i++)
#pragma unroll
      for (int j = 0; j < NT; j++)
        acc2[i][j] = __builtin_amdgcn_mfma_f32_16x16x32_f16(aH[i], bL[j],
                                                            acc2[i][j], 0, 0, 0);
    __builtin_amdgcn_s_setprio(0);
#pragma unroll
    for (int t = 0; t < 4; t++)
      aL[t] = *(const f16x8*)&buf[sub * 4096 + (4 + t) * 512 + lane * 8];
    __builtin_amdgcn_s_setprio(1);
#pragma unroll
    for (int i = 0; i < 4; i++)
#pragma unroll
      for (int j = 0; j < NT; j++)
        acc2[i][j] = __builtin_amdgcn_mfma_f32_16x16x32_f16(aL[i], bH[j],
                                                            acc2[i][j], 0, 0, 0);
    __builtin_amdgcn_s_setprio(0);
  };

#define SB0 __builtin_amdgcn_sched_barrier(0)
#define WAIT_STAGE()                                              \
  do {                                                            \
    if constexpr (NT == 2)                                        \
      asm volatile("s_waitcnt vmcnt(4)" ::: "memory");            \
    else                                                          \
      asm volatile("s_waitcnt vmcnt(2)" ::: "memory");            \
  } while (0)

  // ---- prologue: stage window 0 -> lds0; load B(0); publish lds0.
  stageNext(lds0);                   // S0: 4  (FIFO-oldest)
  loadBNext(b0H, b0L);               // L(k0): 2NT
  WAIT_STAGE();                      // retires S0; L(k0) stays in flight
  __builtin_amdgcn_s_barrier();
  SB0;
  // invariant entering window w: outstanding [L(k0) 2NT]; buf[w] published

  short* cur = lds0;
  short* oth = lds1;
  for (int w = 0; w < W - 1; ++w) {
    loadBNext(b1H, b1L);             // L(k1): 2NT
    stageNext(oth);                  // S(w+1): 4 (other buffer; its reads
                                     // retired before last barrier)
    computeSub(cur, 0, b0H, b0L);    // auto-wait retires L(k0)
    SB0;                             // pin: S issued before L(k2)
    loadBNext(b0H, b0L);             // L(k2): 2NT
    computeSub(cur, 1, b1H, b1L);    // auto-wait retires L(k1)
    SB0;
    WAIT_STAGE();                    // retires S(w+1); L(k2) crosses
    __builtin_amdgcn_s_barrier();    // publish buf[w+1]
    SB0;
    short* t = cur; cur = oth; oth = t;
  }

  // ---- tail window W-1: no stage, no L(k2); compiler auto-waits.
  loadBNext(b1H, b1L);
  computeSub(cur, 0, b0H, b0L);
  computeSub(cur, 1, b1H, b1L);

  // epilogue: combine accs, bias + per-column activation + clip.
  // C/D map col=lane&15, row=quad*4+reg (m89-verified).
  // OUT_F16 path writes PACKED layout (next layer's A): chunkrow=row>>4,
  // kstep=col>>5, lane'=((col>>3)&3)*16 + (row&15), j'=col&7.
#pragma unroll
  for (int j = 0; j < NT; j++) {
    int col = blockN + wave * (NT * 16) + j * 16 + m16;
    float b = bias[col];
    float m = mo[col];
    int a = aid[col];
    size_t kbase = OUT_F16 ? ((size_t)(col >> 5) * MCH) * 512 +
                                 (size_t)((col >> 3) & 3) * 128 + (col & 7)
                           : 0;
#pragma unroll
    for (int i = 0; i < 4; i++) {
#pragma unroll
      for (int r = 0; r < 4; r++) {
        int row = blockM + i * 16 + quad * 4 + r;
        float s = acc1[i][j][r] + acc2[i][j][r] * INV_LO_SCALE;
        float v = rand_act(s + b, a, m);
        if (OUT_F16) {
          unsigned short h, l;
          split_h(v, h, l);
          size_t pidx = kbase + (size_t)(row >> 4) * 512 + (row & 15) * 8;
          Ch[pidx] = h;
          Cl[pidx] = l;
        } else {
          Cf[(size_t)row * N + col] = v;
        }
      }
    }
  }
}

extern "C" void kernel_launch(void* const* d_in, const int* in_sizes, int n_in,
                              void* d_out, int out_size, void* d_ws,
                              size_t ws_size, hipStream_t stream) {
  (void)in_sizes; (void)n_in; (void)out_size; (void)ws_size;

  const float* x     = (const float*)d_in[0];
  const float* W_in  = (const float*)d_in[1];
  const float* b_in  = (const float*)d_in[2];
  const float* Wh[6] = {(const float*)d_in[3], (const float*)d_in[4],
                        (const float*)d_in[5], (const float*)d_in[6],
                        (const float*)d_in[7], (const float*)d_in[8]};
  const float* bh    = (const float*)d_in[9];
  const float* W_out = (const float*)d_in[10];
  const float* b_out = (const float*)d_in[11];
  const float* mo_in = (const float*)d_in[12];
  const float* mo_h  = (const float*)d_in[13];
  const float* mo_out= (const float*)d_in[14];
  const int* aid_in  = (const int*)d_in[15];
  const int* aid_h   = (const int*)d_in[16];
  const int* aid_out = (const int*)d_in[17];

  const int hin[6] = {XDIM, XDIM, 2 * XDIM, XDIM, 2 * XDIM, XDIM};

  // workspace layout (~264 MB); each tensor = hi plane then lo plane (packed)
  char* p = (char*)d_ws;
  auto take = [&](size_t elems) {
    short* q = (short*)p;
    p += elems * 2 * 2;  // hi + lo, 2B each
    return q;
  };
  short* x_s = take((size_t)BDIM * INDIM);
  size_t xpl = (size_t)BDIM * INDIM;
  short* w_in_s = take((size_t)XDIM * INDIM);
  size_t wpl_in = (size_t)XDIM * INDIM;
  short* w_h_s[6];
  size_t wpl_h[6];
  for (int i = 0; i < 6; i++) {
    wpl_h[i] = (size_t)XDIM * hin[i];
    w_h_s[i] = take(wpl_h[i]);
  }
  short* w_out_s = take((size_t)OUTDIM * XDIM);
  size_t wpl_out = (size_t)OUTDIM * XDIM;
  const size_t apl = (size_t)BDIM * XDIM;  // activation plane
  short* actA = take(apl);
  short* actB = take(apl);
  short* actC = take(apl);

  // 1) pack x -> hi/lo fp16 packed
  pack_x<<<dim3(INDIM / 32, BDIM / 64), dim3(256), 0, stream>>>(
      x, (unsigned short*)x_s, (unsigned short*)(x_s + xpl), INDIM);
  // 2) pack all weights: W(K,N) -> packed BT(rows=N, Kdim=K) hi/lo
  pack_w<<<dim3(XDIM / 32, INDIM / 32), dim3(32, 8), 0, stream>>>(
      W_in, (unsigned short*)w_in_s, (unsigned short*)(w_in_s + wpl_in), INDIM,
      XDIM);
  for (int i = 0; i < 6; i++)
    pack_w<<<dim3(XDIM / 32, hin[i] / 32), dim3(32, 8), 0, stream>>>(
        Wh[i], (unsigned short*)w_h_s[i],
        (unsigned short*)(w_h_s[i] + wpl_h[i]), hin[i], XDIM);
  pack_w<<<dim3(OUTDIM / 32, XDIM / 32), dim3(32, 8), 0, stream>>>(
      W_out, (unsigned short*)w_out_s, (unsigned short*)(w_out_s + wpl_out),
      XDIM, OUTDIM);

  // 3) GEMM chain with 3 rotating activation buffers (all NT=2, N=2048)
  auto G = [&](const short* A1, size_t a1pl, const short* A2, size_t a2pl,
               const short* W, size_t wpl, const float* bi, const float* m,
               const int* a, short* Cb, int K, int Ks) {
    dim3 grid(XDIM / 128, BDIM / 64);
    const short* A2h = A2;
    const short* A2l = A2 ? A2 + a2pl : nullptr;
    gemm_split_act<true, 2><<<grid, 256, 0, stream>>>(
        A1, A1 + a1pl, A2h, A2l, W, W + wpl, bi, m, a, (unsigned short*)Cb,
        (unsigned short*)(Cb + apl), nullptr, XDIM, K, Ks);
  };

  // input layer: outs[0]=actA
  G(x_s, xpl, nullptr, 0, w_in_s, wpl_in, b_in, mo_in, aid_in, actA,
    INDIM, INDIM);
  // L0: outs[1]=actB
  G(actA, apl, nullptr, 0, w_h_s[0], wpl_h[0], bh + 0 * XDIM, mo_h + 0 * XDIM,
    aid_h + 0 * XDIM, actB, XDIM, XDIM);
  // L1: outs[2]=actC
  G(actB, apl, nullptr, 0, w_h_s[1], wpl_h[1], bh + 1 * XDIM, mo_h + 1 * XDIM,
    aid_h + 1 * XDIM, actC, XDIM, XDIM);
  // L2 (concat outs2,outs1): outs[3]=actA
  G(actC, apl, actB, apl, w_h_s[2], wpl_h[2], bh + 2 * XDIM, mo_h + 2 * XDIM,
    aid_h + 2 * XDIM, actA, 2 * XDIM, XDIM);
  // L3: outs[4]=actB
  G(actA, apl, nullptr, 0, w_h_s[3], wpl_h[3], bh + 3 * XDIM, mo_h + 3 * XDIM,
    aid_h + 3 * XDIM, actB, XDIM, XDIM);
  // L4 (concat outs4,outs3): outs[5]=actC
  G(actB, apl, actA, apl, w_h_s[4], wpl_h[4], bh + 4 * XDIM, mo_h + 4 * XDIM,
    aid_h + 4 * XDIM, actC, 2 * XDIM, XDIM);
  // L5: outs[6]=actB
  G(actC, apl, nullptr, 0, w_h_s[5], wpl_h[5], bh + 5 * XDIM, mo_h + 5 * XDIM,
    aid_h + 5 * XDIM, actB, XDIM, XDIM);
  // output layer -> d_out (fp32, row-major): N=512 -> NT=1, 64-wide tiles,
  // grid (8,64)=512 blocks = 2 blocks/CU (was 1/CU at 128-wide).
  {
    dim3 grid(OUTDIM / 64, BDIM / 64);
    gemm_split_act<false, 1><<<grid, 256, 0, stream>>>(
        actB, actB + apl, nullptr, nullptr, w_out_s, w_out_s + wpl_out, b_out,
        mo_out, aid_out, nullptr, nullptr, (float*)d_out, OUTDIM, XDIM, XDIM);
  }
}